// Round 4
// baseline (344.666 us; speedup 1.0000x reference)
//
#include <hip/hip_runtime.h>
#include <stdint.h>

#define NB 16
#define NC 128
#define NOC 128
#define NF 64
#define NT 256
#define NCTX 128
#define NTAPS 9
#define NFLAT 147456
#define TEMPR 30.0f

#define ICP 36          // padded ic stride (elements); 72B = 18 banks -> conflict-free b128 reads
#define XCOLS 258       // 256 t + 2 halo cols
#define XROWS 3         // y-1 .. y+1
#define SX_ELEMS (XROWS*XCOLS*ICP)   // 27864
#define SW_ELEMS (NTAPS*NOC*ICP)     // 41472   (total LDS 138.7 KB)

typedef float f32x4 __attribute__((ext_vector_type(4)));
typedef __bf16 bf16x8 __attribute__((ext_vector_type(8)));
typedef __bf16 bf16x2 __attribute__((ext_vector_type(2)));
typedef unsigned int u32x4 __attribute__((ext_vector_type(4)));

// ---------------- kernel 1: attention (16 x softmax over 4) ----------------
__global__ void attn_kernel(const float* __restrict__ g,
                            const float* __restrict__ dk,
                            const float* __restrict__ bias,
                            float* __restrict__ att) {
    int b = threadIdx.x;
    if (b >= NB) return;
    float r0 = bias[0], r1 = bias[1], r2 = bias[2], r3 = bias[3];
    const float* gb = g + b * NCTX;
    for (int c = 0; c < NCTX; ++c) {
        float gv = gb[c];
        r0 += gv * dk[c*4+0];
        r1 += gv * dk[c*4+1];
        r2 += gv * dk[c*4+2];
        r3 += gv * dk[c*4+3];
    }
    r0 *= (1.0f/TEMPR); r1 *= (1.0f/TEMPR); r2 *= (1.0f/TEMPR); r3 *= (1.0f/TEMPR);
    float mx = fmaxf(fmaxf(r0, r1), fmaxf(r2, r3));
    float e0 = expf(r0-mx), e1 = expf(r1-mx), e2 = expf(r2-mx), e3 = expf(r3-mx);
    float s = e0+e1+e2+e3;
    att[b*4+0] = e0/s; att[b*4+1] = e1/s; att[b*4+2] = e2/s; att[b*4+3] = e3/s;
}

// ------- kernel 2: blend 4 banks -> bf16 W[b][tap][oc][ic] -------
__global__ void agg_kernel(const float* __restrict__ w,
                           const float* __restrict__ att,
                           unsigned short* __restrict__ wb) {
    int idx = blockIdx.x * 256 + threadIdx.x;   // 16*128*128 = 262144
    int ic = idx & 127;
    int oc = (idx >> 7) & 127;
    int b  = idx >> 14;
    float a0 = att[b*4+0], a1 = att[b*4+1], a2 = att[b*4+2], a3 = att[b*4+3];
    int d0 = (oc*NC + ic) * NTAPS;
    #pragma unroll
    for (int tap = 0; tap < NTAPS; ++tap) {
        float s = a0 * w[0*NFLAT + d0 + tap]
                + a1 * w[1*NFLAT + d0 + tap]
                + a2 * w[2*NFLAT + d0 + tap]
                + a3 * w[3*NFLAT + d0 + tap];
        __bf16 h = (__bf16)s;
        unsigned short u = *(unsigned short*)&h;
        wb[((b*NTAPS + tap)*NOC + oc)*NC + ic] = u;
    }
}

// ------------------- kernel 3: MFMA implicit-GEMM conv -------------------
// R1 geometry (proven spill-free: 88 VGPR + 64 AGPR): block = 128oc x 256pix,
// 8 waves, wave tile 64x64, acc[4][4]; 1024 blocks.
// + ICP=36 (bank-conflict fix, R2-proven 11x reduction)
// + W prefetched into regs during compute (hides W HBM latency; +36 VGPR only)
// NOTE: acc[4][8] (128 AGPR) forced hipcc's 128-VGPR pin + spills (R2/R3: 265us).
__global__ __launch_bounds__(512) void conv_kernel(
        const float* __restrict__ x,
        const unsigned short* __restrict__ wb,
        float* __restrict__ out) {
    __shared__ unsigned short sx[SX_ELEMS];   // [3][258][36] bf16 bits
    __shared__ unsigned short sw[SW_ELEMS];   // [9][128][36] bf16 bits

    // bijective XCD swizzle: 1024 blocks -> 128 contiguous logical per XCD = 2 batches
    const int p  = blockIdx.x;
    const int lg = (p & 7) * 128 + (p >> 3);
    const int b  = lg >> 6;          // batch
    const int y  = lg & 63;          // output row

    const int tid  = threadIdx.x;
    const int lane = tid & 63;
    const int wid  = tid >> 6;
    const int wpix = wid & 3;    // 64-pix quadrant
    const int woc  = wid >> 2;   // 64-oc half
    const int l15  = lane & 15;
    const int l4   = lane >> 4;

    f32x4 acc[4][4];
    #pragma unroll
    for (int m = 0; m < 4; ++m)
        #pragma unroll
        for (int n = 0; n < 4; ++n)
            acc[m][n] = (f32x4){0.f, 0.f, 0.f, 0.f};

    const float* xb = x + (b * NC) * (NF * NT);
    const unsigned short* wbb = wb + b * (NTAPS * NOC * NC);

    // zero halo cols (t=-1 -> col 0, t=256 -> col 257) once; never overwritten
    if (tid < 96) {
        int i2 = tid & 15;               // ic-pair
        int rr = tid >> 4;               // 0..5
        int r  = rr % 3;
        int c  = (rr / 3) ? (XCOLS - 1) : 0;
        *(unsigned*)(sx + (r * XCOLS + c) * ICP + 2*i2) = 0u;
    }

    // per-thread-constant LDS bases for the compute phase
    const unsigned short* const swp = sw + (woc * 64 + l15) * ICP + l4 * 8;
    const unsigned short* const sxp = sx + (wpix * 64 + l15) * ICP + l4 * 8;

    // W staging decomposition (per thread): row = tap*128+oc, 16B quarter q4
    const int wrow = tid >> 2;
    const int wq4  = tid & 3;
    const unsigned short* const wsrc = wbb + wrow * NC + wq4 * 8;
    unsigned short* const wdst = sw + wrow * ICP + wq4 * 8;

    // prefetch W for c4=0 into registers
    u32x4 wreg[9];
    #pragma unroll
    for (int j = 0; j < 9; ++j)
        wreg[j] = *(const u32x4*)(wsrc + j * 128 * NC);

    for (int c4 = 0; c4 < 4; ++c4) {
        const int ic0 = c4 * 32;
        __syncthreads();   // prev-phase LDS reads done (halo writes visible on c4==0)

        // ---- write prefetched W regs to LDS (9*128 rows x 32 ic)
        #pragma unroll
        for (int j = 0; j < 9; ++j)
            *(u32x4*)(wdst + j * 128 * ICP) = wreg[j];

        // ---- stage X: 3 rows x 256 t x 32 ic, fp32 -> bf16, transposed to [r][c][ic]
        // 3072 items: qlo=w_&3, i2=(w_>>2)&15, qhi=(w_>>6)&15, r=w_>>10; q=qhi*4+qlo
        #pragma unroll
        for (int j = 0; j < 6; ++j) {
            int w_  = tid + j * 512;
            int qlo = w_ & 3;
            int i2  = (w_ >> 2) & 15;
            int qhi = (w_ >> 6) & 15;
            int r   = w_ >> 10;
            int q   = qhi * 4 + qlo;
            int iy  = y - 1 + r;
            f32x4 v0 = (f32x4){0.f,0.f,0.f,0.f};
            f32x4 v1 = v0;
            if ((unsigned)iy < (unsigned)NF) {
                const float* src = xb + ((ic0 + 2*i2) * NF + iy) * NT + q * 4;
                v0 = *(const f32x4*)src;
                v1 = *(const f32x4*)(src + NF * NT);
            }
            unsigned short* dst = sx + (r * XCOLS + q*4 + 1) * ICP + 2*i2;
            #pragma unroll
            for (int jj = 0; jj < 4; ++jj) {
                bf16x2 pk;
                pk[0] = (__bf16)v0[jj];
                pk[1] = (__bf16)v1[jj];
                *(bf16x2*)(dst + jj * ICP) = pk;
            }
        }
        __syncthreads();

        // ---- prefetch W for next c4 (rides the VMEM queue under compute)
        if (c4 < 3) {
            #pragma unroll
            for (int j = 0; j < 9; ++j)
                wreg[j] = *(const u32x4*)(wsrc + j * 128 * NC + (ic0 + 32));
        }

        // ---- compute: 9 taps x (4 A + 4 B reads, 16 MFMA) per wave
        #pragma unroll
        for (int ky = 0; ky < 3; ++ky) {
            #pragma unroll
            for (int kx = 0; kx < 3; ++kx) {
                const int tap = ky * 3 + kx;
                bf16x8 af[4], bfv[4];
                #pragma unroll
                for (int m = 0; m < 4; ++m)
                    af[m] = *(const bf16x8*)(swp + (tap * NOC + m * 16) * ICP);
                #pragma unroll
                for (int n = 0; n < 4; ++n)
                    bfv[n] = *(const bf16x8*)(sxp + (ky * XCOLS + kx + n * 16) * ICP);
                #pragma unroll
                for (int m = 0; m < 4; ++m)
                    #pragma unroll
                    for (int n = 0; n < 4; ++n)
                        acc[m][n] = __builtin_amdgcn_mfma_f32_16x16x32_bf16(
                            af[m], bfv[n], acc[m][n], 0, 0, 0);
            }
        }
    }

    // ---- epilogue: D[row=oc=(l>>4)*4+r][col=pix=l&15]
    #pragma unroll
    for (int m = 0; m < 4; ++m) {
        int ocb = woc * 64 + m * 16 + l4 * 4;
        #pragma unroll
        for (int r = 0; r < 4; ++r) {
            float* orow = out + ((b * NOC + ocb + r) * NF + y) * NT;
            #pragma unroll
            for (int n = 0; n < 4; ++n)
                orow[wpix * 64 + n * 16 + l15] = acc[m][n][r];
        }
    }
}

extern "C" void kernel_launch(void* const* d_in, const int* in_sizes, int n_in,
                              void* d_out, int out_size, void* d_ws, size_t ws_size,
                              hipStream_t stream) {
    const float* x    = (const float*)d_in[0];
    const float* g    = (const float*)d_in[1];
    const float* dk   = (const float*)d_in[2];
    const float* bias = (const float*)d_in[3];
    const float* w    = (const float*)d_in[4];
    float* out = (float*)d_out;

    float* att = (float*)d_ws;                                  // 64 floats
    unsigned short* wb = (unsigned short*)((char*)d_ws + 256);  // 16*9*128*128 bf16

    attn_kernel<<<dim3(1), dim3(64), 0, stream>>>(g, dk, bias, att);
    agg_kernel<<<dim3(1024), dim3(256), 0, stream>>>(w, att, wb);
    conv_kernel<<<dim3(1024), dim3(512), 0, stream>>>(x, wb, out);
}

// Round 5
// 124.526 us; speedup vs baseline: 2.7678x; 2.7678x over previous
//
#include <hip/hip_runtime.h>
#include <stdint.h>

#define NB 16
#define NC 128
#define NOC 128
#define NF 64
#define NT 256
#define NCTX 128
#define NTAPS 9
#define NFLAT 147456
#define TEMPR 30.0f

#define XCOLS 258       // 256 t + 2 halo cols
#define XROWS 3         // y-1 .. y+1
// K-major LDS: 16B chunk = 8 ic elems. sx chunks: [r:3][kq:4][col:258]; sw chunks: [tap:9][kq:4][oc:128]
#define SX_CHUNKS (XROWS*4*XCOLS)    // 3096  -> 49536 B
#define SW_CHUNKS (NTAPS*4*NOC)      // 4608  -> 73728 B  (total 120.4 KB)

typedef float f32x4 __attribute__((ext_vector_type(4)));
typedef __bf16 bf16x8 __attribute__((ext_vector_type(8)));
typedef unsigned int u32x4 __attribute__((ext_vector_type(4)));

// ---------------- kernel 1: attention (16 x softmax over 4) ----------------
__global__ void attn_kernel(const float* __restrict__ g,
                            const float* __restrict__ dk,
                            const float* __restrict__ bias,
                            float* __restrict__ att) {
    int b = threadIdx.x;
    if (b >= NB) return;
    float r0 = bias[0], r1 = bias[1], r2 = bias[2], r3 = bias[3];
    const float* gb = g + b * NCTX;
    for (int c = 0; c < NCTX; ++c) {
        float gv = gb[c];
        r0 += gv * dk[c*4+0];
        r1 += gv * dk[c*4+1];
        r2 += gv * dk[c*4+2];
        r3 += gv * dk[c*4+3];
    }
    r0 *= (1.0f/TEMPR); r1 *= (1.0f/TEMPR); r2 *= (1.0f/TEMPR); r3 *= (1.0f/TEMPR);
    float mx = fmaxf(fmaxf(r0, r1), fmaxf(r2, r3));
    float e0 = expf(r0-mx), e1 = expf(r1-mx), e2 = expf(r2-mx), e3 = expf(r3-mx);
    float s = e0+e1+e2+e3;
    att[b*4+0] = e0/s; att[b*4+1] = e1/s; att[b*4+2] = e2/s; att[b*4+3] = e3/s;
}

// ------- kernel 2: blend 4 banks -> bf16 W in K-major: [b][c4:4][tap:9][kq:4][oc:128][8]
__global__ void agg_kernel(const float* __restrict__ w,
                           const float* __restrict__ att,
                           unsigned short* __restrict__ wb) {
    int idx = blockIdx.x * 256 + threadIdx.x;   // 16*128*128 = 262144
    int ic = idx & 127;
    int oc = (idx >> 7) & 127;
    int b  = idx >> 14;
    float a0 = att[b*4+0], a1 = att[b*4+1], a2 = att[b*4+2], a3 = att[b*4+3];
    int d0 = (oc*NC + ic) * NTAPS;
    int c4 = ic >> 5;
    int kq = (ic >> 3) & 3;
    int e  = ic & 7;
    #pragma unroll
    for (int tap = 0; tap < NTAPS; ++tap) {
        float s = a0 * w[0*NFLAT + d0 + tap]
                + a1 * w[1*NFLAT + d0 + tap]
                + a2 * w[2*NFLAT + d0 + tap]
                + a3 * w[3*NFLAT + d0 + tap];
        __bf16 h = (__bf16)s;
        unsigned short u = *(unsigned short*)&h;
        int chunk = (tap * 4 + kq) * 128 + oc;                    // within c4 block
        wb[(((b * 4 + c4) * (NTAPS*4*NOC)) + chunk) * 8 + e] = u;
    }
}

// ------------------- kernel 3: MFMA implicit-GEMM conv -------------------
// R1 geometry (proven: 88 VGPR + 64 AGPR, no spill): block = 128oc x 256pix,
// 8 waves, wave tile 64x64, acc[4][4]; 1024 blocks.
// K-major LDS (16B chunks, zero padding): every ds_*_b128 is 16B-aligned
// (ICP=34/36 byte-strides silently split b128 into b32s -> R2-R4 collapse)
// and chunk-consecutive lanes give conflict-free bank sweeps.
__global__ __launch_bounds__(512) void conv_kernel(
        const float* __restrict__ x,
        const unsigned short* __restrict__ wb,
        float* __restrict__ out) {
    __shared__ unsigned short sx[SX_CHUNKS * 8];   // [r][kq][col] 16B chunks
    __shared__ unsigned short sw[SW_CHUNKS * 8];   // [tap][kq][oc] 16B chunks

    // bijective XCD swizzle: 1024 blocks -> 128 contiguous logical per XCD = 2 batches
    const int p  = blockIdx.x;
    const int lg = (p & 7) * 128 + (p >> 3);
    const int b  = lg >> 6;          // batch
    const int y  = lg & 63;          // output row

    const int tid  = threadIdx.x;
    const int lane = tid & 63;
    const int wid  = tid >> 6;
    const int wpix = wid & 3;    // 64-pix quadrant
    const int woc  = wid >> 2;   // 64-oc half
    const int l15  = lane & 15;
    const int l4   = lane >> 4;

    f32x4 acc[4][4];
    #pragma unroll
    for (int m = 0; m < 4; ++m)
        #pragma unroll
        for (int n = 0; n < 4; ++n)
            acc[m][n] = (f32x4){0.f, 0.f, 0.f, 0.f};

    const float* xb = x + (b * NC) * (NF * NT);
    const unsigned short* wbb = wb + b * (NTAPS * NOC * NC);

    // zero halo cols (t=-1 -> col 0, t=256 -> col 257) once; never overwritten
    // 24 chunks x 16B = 96 x 4B pieces
    if (tid < 96) {
        int piece = tid & 3;
        int gch   = tid >> 2;          // 0..23
        int r     = gch / 8;
        int rem   = gch & 7;
        int kq    = rem >> 1;
        int c     = (rem & 1) ? (XCOLS - 1) : 0;
        *(unsigned*)(sx + (((r * 4 + kq) * XCOLS + c) * 8) + piece * 2) = 0u;
    }

    // per-thread-constant LDS bases for the compute phase (shorts)
    const unsigned short* const swp = sw + (l4 * NOC + woc * 64 + l15) * 8;
    const unsigned short* const sxp = sx + (l4 * XCOLS + wpix * 64 + l15) * 8;

    for (int c4 = 0; c4 < 4; ++c4) {
        const int ic0 = c4 * 32;
        __syncthreads();   // prev-phase LDS reads done (halo writes visible on c4==0)

        // ---- stage X: 3 rows x 256 t x 32 ic, fp32 -> bf16, K-major
        // 3072 items: qlo=w_&3, i2=(w_>>2)&15, qhi=(w_>>6)&15, r=w_>>10; q=qhi*4+qlo
        #pragma unroll
        for (int j = 0; j < 6; ++j) {
            int w_  = tid + j * 512;
            int qlo = w_ & 3;
            int i2  = (w_ >> 2) & 15;
            int qhi = (w_ >> 6) & 15;
            int r   = w_ >> 10;
            int q   = qhi * 4 + qlo;
            int iy  = y - 1 + r;
            f32x4 v0 = (f32x4){0.f,0.f,0.f,0.f};
            f32x4 v1 = v0;
            if ((unsigned)iy < (unsigned)NF) {
                const float* src = xb + ((ic0 + 2*i2) * NF + iy) * NT + q * 4;
                v0 = *(const f32x4*)src;
                v1 = *(const f32x4*)(src + NF * NT);
            }
            const int kq = i2 >> 2;            // 16B chunk holding ic = ic0+kq*8+e
            const int e0 = (2 * i2) & 7;       // even; v1 goes to e0+1
            unsigned short* dst = sx + ((r * 4 + kq) * XCOLS + q * 4 + 1) * 8 + e0;
            #pragma unroll
            for (int jj = 0; jj < 4; ++jj) {
                __bf16 h0 = (__bf16)v0[jj];
                __bf16 h1 = (__bf16)v1[jj];
                unsigned pk = (unsigned)*(unsigned short*)&h0
                            | ((unsigned)*(unsigned short*)&h1 << 16);
                *(unsigned*)(dst + jj * 8) = pk;   // next col = +1 chunk = +8 shorts
            }
        }

        // ---- stage W: straight coalesced memcpy of this c4's 73728 B
        const unsigned short* wsrc = wbb + c4 * (SW_CHUNKS * 8);
        #pragma unroll
        for (int j = 0; j < 9; ++j) {
            int chunk = tid + j * 512;          // 0..4607
            u32x4 d = *(const u32x4*)(wsrc + chunk * 8);
            *(u32x4*)(sw + chunk * 8) = d;
        }
        __syncthreads();

        // ---- compute: 9 taps x (4 A + 4 B b128 reads, 16 MFMA) per wave
        #pragma unroll
        for (int ky = 0; ky < 3; ++ky) {
            #pragma unroll
            for (int kx = 0; kx < 3; ++kx) {
                const int tap = ky * 3 + kx;
                bf16x8 af[4], bfv[4];
                #pragma unroll
                for (int m = 0; m < 4; ++m)
                    af[m] = *(const bf16x8*)(swp + (tap * 4 * NOC + m * 16) * 8);
                #pragma unroll
                for (int n = 0; n < 4; ++n)
                    bfv[n] = *(const bf16x8*)(sxp + (ky * 4 * XCOLS + kx + n * 16) * 8);
                #pragma unroll
                for (int m = 0; m < 4; ++m)
                    #pragma unroll
                    for (int n = 0; n < 4; ++n)
                        acc[m][n] = __builtin_amdgcn_mfma_f32_16x16x32_bf16(
                            af[m], bfv[n], acc[m][n], 0, 0, 0);
            }
        }
    }

    // ---- epilogue: D[row=oc=(l>>4)*4+r][col=pix=l&15]
    #pragma unroll
    for (int m = 0; m < 4; ++m) {
        int ocb = woc * 64 + m * 16 + l4 * 4;
        #pragma unroll
        for (int r = 0; r < 4; ++r) {
            float* orow = out + ((b * NOC + ocb + r) * NF + y) * NT;
            #pragma unroll
            for (int n = 0; n < 4; ++n)
                orow[wpix * 64 + n * 16 + l15] = acc[m][n][r];
        }
    }
}

extern "C" void kernel_launch(void* const* d_in, const int* in_sizes, int n_in,
                              void* d_out, int out_size, void* d_ws, size_t ws_size,
                              hipStream_t stream) {
    const float* x    = (const float*)d_in[0];
    const float* g    = (const float*)d_in[1];
    const float* dk   = (const float*)d_in[2];
    const float* bias = (const float*)d_in[3];
    const float* w    = (const float*)d_in[4];
    float* out = (float*)d_out;

    float* att = (float*)d_ws;                                  // 64 floats
    unsigned short* wb = (unsigned short*)((char*)d_ws + 256);  // 16*9*128*128 bf16, K-major

    attn_kernel<<<dim3(1), dim3(64), 0, stream>>>(g, dk, bias, att);
    agg_kernel<<<dim3(1024), dim3(256), 0, stream>>>(w, att, wb);
    conv_kernel<<<dim3(1024), dim3(512), 0, stream>>>(x, wb, out);
}

// Round 6
// 118.616 us; speedup vs baseline: 2.9057x; 1.0498x over previous
//
#include <hip/hip_runtime.h>
#include <stdint.h>

#define NB 16
#define NC 128
#define NOC 128
#define NF 64
#define NT 256
#define NCTX 128
#define NTAPS 9
#define NFLAT 147456
#define TEMPR 30.0f

#define XCOLS 258       // 256 t + 2 halo cols
#define XROWS 3         // y-1 .. y+1
// K-major LDS: 16B chunk = 8 ic elems. sx chunks: [r:3][kq:4][col:258]; sw chunks: [tap:9][kq:4][oc:128]
#define SX_CHUNKS (XROWS*4*XCOLS)    // 3096  -> 49536 B
#define SW_CHUNKS (NTAPS*4*NOC)      // 4608  -> 73728 B  (total 120.4 KB)

typedef float f32x4 __attribute__((ext_vector_type(4)));
typedef __bf16 bf16x8 __attribute__((ext_vector_type(8)));
typedef unsigned int u32x4 __attribute__((ext_vector_type(4)));

// ---------------- kernel 1: attention (16 x softmax over 4) ----------------
__global__ void attn_kernel(const float* __restrict__ g,
                            const float* __restrict__ dk,
                            const float* __restrict__ bias,
                            float* __restrict__ att) {
    int b = threadIdx.x;
    if (b >= NB) return;
    float r0 = bias[0], r1 = bias[1], r2 = bias[2], r3 = bias[3];
    const float* gb = g + b * NCTX;
    for (int c = 0; c < NCTX; ++c) {
        float gv = gb[c];
        r0 += gv * dk[c*4+0];
        r1 += gv * dk[c*4+1];
        r2 += gv * dk[c*4+2];
        r3 += gv * dk[c*4+3];
    }
    r0 *= (1.0f/TEMPR); r1 *= (1.0f/TEMPR); r2 *= (1.0f/TEMPR); r3 *= (1.0f/TEMPR);
    float mx = fmaxf(fmaxf(r0, r1), fmaxf(r2, r3));
    float e0 = expf(r0-mx), e1 = expf(r1-mx), e2 = expf(r2-mx), e3 = expf(r3-mx);
    float s = e0+e1+e2+e3;
    att[b*4+0] = e0/s; att[b*4+1] = e1/s; att[b*4+2] = e2/s; att[b*4+3] = e3/s;
}

// ------- kernel 2: blend 4 banks -> bf16 W in K-major: [b][c4:4][tap:9][kq:4][oc:128][8]
__global__ void agg_kernel(const float* __restrict__ w,
                           const float* __restrict__ att,
                           unsigned short* __restrict__ wb) {
    int idx = blockIdx.x * 256 + threadIdx.x;   // 16*128*128 = 262144
    int ic = idx & 127;
    int oc = (idx >> 7) & 127;
    int b  = idx >> 14;
    float a0 = att[b*4+0], a1 = att[b*4+1], a2 = att[b*4+2], a3 = att[b*4+3];
    int d0 = (oc*NC + ic) * NTAPS;
    int c4 = ic >> 5;
    int kq = (ic >> 3) & 3;
    int e  = ic & 7;
    #pragma unroll
    for (int tap = 0; tap < NTAPS; ++tap) {
        float s = a0 * w[0*NFLAT + d0 + tap]
                + a1 * w[1*NFLAT + d0 + tap]
                + a2 * w[2*NFLAT + d0 + tap]
                + a3 * w[3*NFLAT + d0 + tap];
        __bf16 h = (__bf16)s;
        unsigned short u = *(unsigned short*)&h;
        int chunk = (tap * 4 + kq) * 128 + oc;                    // within c4 block
        wb[(((b * 4 + c4) * (NTAPS*4*NOC)) + chunk) * 8 + e] = u;
    }
}

// ------------------- kernel 3: MFMA implicit-GEMM conv -------------------
// R5 structure (K-major 16B-chunk LDS, proven) + T14 reg-prefetch pipeline:
// next c4's X/W global loads issue at the top of compute and fly under MFMA;
// staging phase is then pure reg->LDS writes between the two barriers.
// X-write bank fix: q = qhi*4 + ((qlo+i2)&3) mixes i2 parity into the
// weight-16 bank bit -> 2-way on 32 banks (free) instead of 4-way on 16.
__global__ __launch_bounds__(512) void conv_kernel(
        const float* __restrict__ x,
        const unsigned short* __restrict__ wb,
        float* __restrict__ out) {
    __shared__ unsigned short sx[SX_CHUNKS * 8];   // [r][kq][col] 16B chunks
    __shared__ unsigned short sw[SW_CHUNKS * 8];   // [tap][kq][oc] 16B chunks

    // bijective XCD swizzle: 1024 blocks -> 128 contiguous logical per XCD = 2 batches
    const int p  = blockIdx.x;
    const int lg = (p & 7) * 128 + (p >> 3);
    const int b  = lg >> 6;          // batch
    const int y  = lg & 63;          // output row

    const int tid  = threadIdx.x;
    const int lane = tid & 63;
    const int wid  = tid >> 6;
    const int wpix = wid & 3;    // 64-pix quadrant
    const int woc  = wid >> 2;   // 64-oc half
    const int l15  = lane & 15;
    const int l4   = lane >> 4;

    f32x4 acc[4][4];
    #pragma unroll
    for (int m = 0; m < 4; ++m)
        #pragma unroll
        for (int n = 0; n < 4; ++n)
            acc[m][n] = (f32x4){0.f, 0.f, 0.f, 0.f};

    const float* xb = x + (b * NC) * (NF * NT);
    const unsigned short* wbb = wb + b * (NTAPS * NOC * NC);

    // zero halo cols (t=-1 -> col 0, t=256 -> col 257) once; never overwritten
    if (tid < 96) {
        int piece = tid & 3;
        int gch   = tid >> 2;          // 0..23
        int r     = gch / 8;
        int rem   = gch & 7;
        int kq    = rem >> 1;
        int c     = (rem & 1) ? (XCOLS - 1) : 0;
        *(unsigned*)(sx + (((r * 4 + kq) * XCOLS + c) * 8) + piece * 2) = 0u;
    }

    // per-thread-constant LDS bases for the compute phase (shorts)
    const unsigned short* const swp = sw + (l4 * NOC + woc * 64 + l15) * 8;
    const unsigned short* const sxp = sx + (l4 * XCOLS + wpix * 64 + l15) * 8;

    // ---- X staging decomposition (per thread, j in 0..5 handled via hi=(tid>>6)+8j)
    const int qlo = tid & 3;
    const int i2  = (tid >> 2) & 15;
    const int xkq = i2 >> 2;
    const int e0  = (2 * i2) & 7;
    const int qsw = (qlo + i2) & 3;     // bank-mix column swap (bijective per 4-lane group)

    // prefetch registers
    f32x4 xv0[6], xv1[6];
    u32x4 wreg[9];

    auto issue_x = [&](int c4) {
        const int ic0 = c4 * 32;
        #pragma unroll
        for (int j = 0; j < 6; ++j) {
            int hi  = (tid >> 6) + 8 * j;
            int qhi = hi & 15;
            int r   = hi >> 4;
            int q   = qhi * 4 + qsw;
            int iy  = y - 1 + r;
            f32x4 v0 = (f32x4){0.f,0.f,0.f,0.f};
            f32x4 v1 = v0;
            if ((unsigned)iy < (unsigned)NF) {
                const float* src = xb + ((ic0 + 2*i2) * NF + iy) * NT + q * 4;
                v0 = *(const f32x4*)src;
                v1 = *(const f32x4*)(src + NF * NT);
            }
            xv0[j] = v0;
            xv1[j] = v1;
        }
    };
    auto issue_w = [&](int c4) {
        const unsigned short* wsrc = wbb + c4 * (SW_CHUNKS * 8);
        #pragma unroll
        for (int j = 0; j < 9; ++j)
            wreg[j] = *(const u32x4*)(wsrc + (tid + j * 512) * 8);
    };

    issue_x(0);
    issue_w(0);

    for (int c4 = 0; c4 < 4; ++c4) {
        __syncthreads();   // prev compute's LDS reads done (halo visible on c4==0)

        // ---- write prefetched X regs -> LDS (K-major, bank-balanced 2-way)
        #pragma unroll
        for (int j = 0; j < 6; ++j) {
            int hi  = (tid >> 6) + 8 * j;
            int qhi = hi & 15;
            int r   = hi >> 4;
            int q   = qhi * 4 + qsw;
            unsigned short* dst = sx + ((r * 4 + xkq) * XCOLS + q * 4 + 1) * 8 + e0;
            #pragma unroll
            for (int jj = 0; jj < 4; ++jj) {
                __bf16 h0 = (__bf16)xv0[j][jj];
                __bf16 h1 = (__bf16)xv1[j][jj];
                unsigned pk = (unsigned)*(unsigned short*)&h0
                            | ((unsigned)*(unsigned short*)&h1 << 16);
                *(unsigned*)(dst + jj * 8) = pk;   // next col = +1 chunk = +8 shorts
            }
        }

        // ---- write prefetched W regs -> LDS (straight 16B copies)
        #pragma unroll
        for (int j = 0; j < 9; ++j)
            *(u32x4*)(sw + (tid + j * 512) * 8) = wreg[j];

        __syncthreads();

        // ---- issue next c4's global loads; they complete under the MFMA below
        if (c4 < 3) {
            issue_x(c4 + 1);
            issue_w(c4 + 1);
        }

        // ---- compute: 9 taps x (4 A + 4 B b128 reads, 16 MFMA) per wave
        #pragma unroll
        for (int ky = 0; ky < 3; ++ky) {
            #pragma unroll
            for (int kx = 0; kx < 3; ++kx) {
                const int tap = ky * 3 + kx;
                bf16x8 af[4], bfv[4];
                #pragma unroll
                for (int m = 0; m < 4; ++m)
                    af[m] = *(const bf16x8*)(swp + (tap * 4 * NOC + m * 16) * 8);
                #pragma unroll
                for (int n = 0; n < 4; ++n)
                    bfv[n] = *(const bf16x8*)(sxp + (ky * 4 * XCOLS + kx + n * 16) * 8);
                #pragma unroll
                for (int m = 0; m < 4; ++m)
                    #pragma unroll
                    for (int n = 0; n < 4; ++n)
                        acc[m][n] = __builtin_amdgcn_mfma_f32_16x16x32_bf16(
                            af[m], bfv[n], acc[m][n], 0, 0, 0);
            }
        }
    }

    // ---- epilogue: D[row=oc=(l>>4)*4+r][col=pix=l&15]
    #pragma unroll
    for (int m = 0; m < 4; ++m) {
        int ocb = woc * 64 + m * 16 + l4 * 4;
        #pragma unroll
        for (int r = 0; r < 4; ++r) {
            float* orow = out + ((b * NOC + ocb + r) * NF + y) * NT;
            #pragma unroll
            for (int n = 0; n < 4; ++n)
                orow[wpix * 64 + n * 16 + l15] = acc[m][n][r];
        }
    }
}

extern "C" void kernel_launch(void* const* d_in, const int* in_sizes, int n_in,
                              void* d_out, int out_size, void* d_ws, size_t ws_size,
                              hipStream_t stream) {
    const float* x    = (const float*)d_in[0];
    const float* g    = (const float*)d_in[1];
    const float* dk   = (const float*)d_in[2];
    const float* bias = (const float*)d_in[3];
    const float* w    = (const float*)d_in[4];
    float* out = (float*)d_out;

    float* att = (float*)d_ws;                                  // 64 floats
    unsigned short* wb = (unsigned short*)((char*)d_ws + 256);  // 16*9*128*128 bf16, K-major

    attn_kernel<<<dim3(1), dim3(64), 0, stream>>>(g, dk, bias, att);
    agg_kernel<<<dim3(1024), dim3(256), 0, stream>>>(w, att, wb);
    conv_kernel<<<dim3(1024), dim3(512), 0, stream>>>(x, wb, out);
}